// Round 6
// baseline (478.825 us; speedup 1.0000x reference)
//
#include <hip/hip_runtime.h>
#include <stdint.h>

#define NROWS 100000   // N rows of x
#define DIMD  128      // D
#define KKIDX 3        // K indices per batch row
#define NDOUT 128      // DOUT
#define KDIM  384      // K*D (nonpool reduction dim)
#define NBAT  500000   // B batch rows

typedef float  f4v  __attribute__((ext_vector_type(4)));
typedef short  s8v  __attribute__((ext_vector_type(8)));
typedef short  s4v  __attribute__((ext_vector_type(4)));

__device__ __forceinline__ short f2bf(float f) {
    union { float f; uint32_t u; } c; c.f = f;
    uint32_t u = c.u;
    uint32_t r = (u + 0x7FFFu + ((u >> 16) & 1u)) >> 16;   // RNE
    return (short)r;
}
__device__ __forceinline__ float bf2f(unsigned short h) {
    union { uint32_t u; float f; } c; c.u = ((uint32_t)h) << 16;
    return c.f;
}
// convert 8 consecutive f32 -> 8 bf16
__device__ __forceinline__ s8v cvt8(const float* __restrict__ p) {
    f4v v0 = *(const f4v*)p;
    f4v v1 = *(const f4v*)(p + 4);
    s8v a;
    a[0] = f2bf(v0[0]); a[1] = f2bf(v0[1]); a[2] = f2bf(v0[2]); a[3] = f2bf(v0[3]);
    a[4] = f2bf(v1[0]); a[5] = f2bf(v1[1]); a[6] = f2bf(v1[2]); a[7] = f2bf(v1[3]);
    return a;
}

// ---- prep: blocks 0..399 = f32 column-sum partials of x;
// ----       blocks 400..447 = weight -> bf16 wT2[(s*128+j)][d] = w[(s*128+d)*128+j]
__global__ void k_prep(const float* __restrict__ x, float* __restrict__ xpool_part,
                       const float* __restrict__ w, unsigned short* __restrict__ wT2) {
    if (blockIdx.x >= 400) {
        int b = blockIdx.x - 400;                     // 0..47
        #pragma unroll
        for (int t = 0; t < 4; ++t) {
            int g = b * 1024 + t * 256 + threadIdx.x; // covers 49152 = KDIM*NDOUT
            int k = g >> 7;                           // input row 0..383
            int n = g & 127;                          // out col
            int s = k >> 7, d = k & 127;
            wT2[(s * 128 + n) * 128 + d] = (unsigned short)f2bf(w[g]);
        }
        return;
    }
    __shared__ float red[256];
    int col  = threadIdx.x & 127;
    int half = threadIdx.x >> 7;
    float acc = 0.f;
    int r0 = blockIdx.x * 250;                        // 400 * 250 = 100000
    for (int r = r0 + half; r < r0 + 250; r += 2)
        acc += x[r * DIMD + col];
    red[threadIdx.x] = acc;
    __syncthreads();
    if (threadIdx.x < 128)
        xpool_part[blockIdx.x * 128 + threadIdx.x] = red[threadIdx.x] + red[threadIdx.x + 128];
}

// ---- reduce partials -> pool_out[j] = sum_d xpool[d]*w[(384+d)*128+j] (f32 exact) ----
__global__ void k_pool(const float* __restrict__ part, const float* __restrict__ w,
                       float* __restrict__ pool_out) {
    __shared__ float xp[128];
    int j = threadIdx.x;   // 128 threads
    float s = 0.f;
    for (int b = 0; b < 400; ++b) s += part[b * 128 + j];
    xp[j] = s;
    __syncthreads();
    float acc = 0.f;
    for (int d = 0; d < DIMD; ++d)
        acc += xp[d] * w[(KDIM + d) * NDOUT + j];
    pool_out[j] = acc;
}

// ---- phase 1: Z[r][jj] = sum_d x[r][d] * wT2[jj][d],  r<100000, jj<384 ----
// block = 256 thr (4 waves); wave = 32 rows x 96 cols (col-group = wave id).
// No LDS, no barriers; K=128 = 4 ksteps. acc[2][6] = 48 VGPR.
__global__ __launch_bounds__(256, 4)
void k_zgemm(const float* __restrict__ x, const unsigned short* __restrict__ wT2,
             unsigned short* __restrict__ zbf) {
    const int tid  = threadIdx.x;
    const int wave = tid >> 6;                        // col-group 0..3
    const int lane = tid & 63;
    const int quad = lane >> 4;
    const int l16  = lane & 15;
    const int rowb  = blockIdx.x * 32;                // 3125*32 = 100000 exact
    const int jbase = wave * 96;

    f4v acc[2][6];
    #pragma unroll
    for (int mt = 0; mt < 2; ++mt)
        #pragma unroll
        for (int nt = 0; nt < 6; ++nt) {
            f4v z = {0.f, 0.f, 0.f, 0.f};
            acc[mt][nt] = z;
        }

    const float* xr0 = x + (rowb + l16) * DIMD;
    const float* xr1 = x + (rowb + 16 + l16) * DIMD;

    #pragma unroll
    for (int kk = 0; kk < 4; ++kk) {
        const int cb = kk * 32 + quad * 8;
        s8v aF0 = cvt8(xr0 + cb);
        s8v aF1 = cvt8(xr1 + cb);
        #pragma unroll
        for (int nt = 0; nt < 6; ++nt) {
            s8v bF = *(const s8v*)(wT2 + (jbase + nt * 16 + l16) * DIMD + cb);
            // swapped operands: acc[mt][nt][i] = Z[rowb+mt*16+l16][jbase+nt*16+quad*4+i]
            acc[0][nt] = __builtin_amdgcn_mfma_f32_16x16x32_bf16(bF, aF0, acc[0][nt], 0, 0, 0);
            acc[1][nt] = __builtin_amdgcn_mfma_f32_16x16x32_bf16(bF, aF1, acc[1][nt], 0, 0, 0);
        }
    }

    #pragma unroll
    for (int nt = 0; nt < 6; ++nt)
        #pragma unroll
        for (int mt = 0; mt < 2; ++mt) {
            int r = rowb + mt * 16 + l16;
            int c = jbase + nt * 16 + quad * 4;
            s4v v;
            v[0] = f2bf(acc[mt][nt][0]); v[1] = f2bf(acc[mt][nt][1]);
            v[2] = f2bf(acc[mt][nt][2]); v[3] = f2bf(acc[mt][nt][3]);
            *(s4v*)(zbf + r * KDIM + c) = v;                 // 8B store
        }
}

// ---- phase 2: out[b][c] = pool[c] + sum_s Z[idx[b,s]][s*128+c] ----
// 16-lane group owns one row-slice: lane l16 handles cols l16*8..+8 (16B gathers,
// 32B coalesced stores). No barriers; TLP + 2-row unroll hides LLC latency.
__global__ __launch_bounds__(256, 6)
void k_scatter(const int* __restrict__ idx, const unsigned short* __restrict__ zbf,
               const float* __restrict__ pool, float* __restrict__ out) {
    const int tid  = threadIdx.x;
    const int l16  = tid & 15;
    const int rgrp = tid >> 4;                        // 0..15 row slot per block-iter
    const int c0   = l16 * 8;
    f4v pv0 = *(const f4v*)(pool + c0);
    f4v pv1 = *(const f4v*)(pool + c0 + 4);
    const int stride = gridDim.x * 16;

    for (int r = blockIdx.x * 16 + rgrp; r < NBAT; r += 2 * stride) {
        const int r2 = r + stride;
        const bool has2 = (r2 < NBAT);

        int i0 = idx[r * 3 + 0], i1 = idx[r * 3 + 1], i2 = idx[r * 3 + 2];
        s8v z0 = *(const s8v*)(zbf + i0 * KDIM +   0 + c0);
        s8v z1 = *(const s8v*)(zbf + i1 * KDIM + 128 + c0);
        s8v z2 = *(const s8v*)(zbf + i2 * KDIM + 256 + c0);

        s8v y0 = z0, y1 = z0, y2 = z0;                // placeholders
        int q0 = 0, q1 = 0, q2 = 0;
        if (has2) {
            q0 = idx[r2 * 3 + 0]; q1 = idx[r2 * 3 + 1]; q2 = idx[r2 * 3 + 2];
            y0 = *(const s8v*)(zbf + q0 * KDIM +   0 + c0);
            y1 = *(const s8v*)(zbf + q1 * KDIM + 128 + c0);
            y2 = *(const s8v*)(zbf + q2 * KDIM + 256 + c0);
        }

        f4v o0 = pv0, o1 = pv1;
        #pragma unroll
        for (int e = 0; e < 4; ++e) {
            o0[e] += bf2f((unsigned short)z0[e])     + bf2f((unsigned short)z1[e])
                   + bf2f((unsigned short)z2[e]);
            o1[e] += bf2f((unsigned short)z0[e + 4]) + bf2f((unsigned short)z1[e + 4])
                   + bf2f((unsigned short)z2[e + 4]);
        }
        float* op = out + (size_t)r * NDOUT + c0;
        __builtin_nontemporal_store(o0, (f4v*)op);
        __builtin_nontemporal_store(o1, (f4v*)(op + 4));

        if (has2) {
            f4v p0 = pv0, p1 = pv1;
            #pragma unroll
            for (int e = 0; e < 4; ++e) {
                p0[e] += bf2f((unsigned short)y0[e])     + bf2f((unsigned short)y1[e])
                       + bf2f((unsigned short)y2[e]);
                p1[e] += bf2f((unsigned short)y0[e + 4]) + bf2f((unsigned short)y1[e + 4])
                       + bf2f((unsigned short)y2[e + 4]);
            }
            float* op2 = out + (size_t)r2 * NDOUT + c0;
            __builtin_nontemporal_store(p0, (f4v*)op2);
            __builtin_nontemporal_store(p1, (f4v*)(op2 + 4));
        }
    }
}

// ---- safety-net fallback (only if workspace < 77 MB; evidence says ws ~1 GB) ----
__global__ void k_fb(const float* __restrict__ x, const int* __restrict__ idx,
                     const float* __restrict__ w, const float* __restrict__ pool,
                     float* __restrict__ out) {
    int b = blockIdx.x;
    int j = threadIdx.x;                              // 128 threads
    float acc = pool[j];
    #pragma unroll
    for (int s = 0; s < KKIDX; ++s) {
        int ir = idx[b * 3 + s];
        const float* xr = x + ir * DIMD;
        for (int d = 0; d < DIMD; ++d)
            acc += xr[d] * w[(s * 128 + d) * NDOUT + j];
    }
    out[(size_t)b * NDOUT + j] = acc;
}

extern "C" void kernel_launch(void* const* d_in, const int* in_sizes, int n_in,
                              void* d_out, int out_size, void* d_ws, size_t ws_size,
                              hipStream_t stream) {
    const float* x   = (const float*)d_in[0];
    const int*   idx = (const int*)d_in[1];
    const float* w   = (const float*)d_in[2];
    float*       out = (float*)d_out;

    char* ws = (char*)d_ws;
    float* pool_out        = (float*)ws;                       // 512 B
    float* xpool_part      = (float*)(ws + 512);               // 400*128*4 = 204800 B
    unsigned short* wT2    = (unsigned short*)(ws + 205312);   // 98304 B
    unsigned short* zbf    = (unsigned short*)(ws + 303616);   // 100000*384*2 = 76.8 MB
    const size_t NEED      = 303616 + (size_t)NROWS * KDIM * 2;

    if (ws_size >= NEED) {
        k_prep <<<448, 256, 0, stream>>>(x, xpool_part, w, wT2);
        k_zgemm<<<3125, 256, 0, stream>>>(x, wT2, zbf);
        k_pool <<<1, 128, 0, stream>>>(xpool_part, w, pool_out);
        k_scatter<<<2048, 256, 0, stream>>>(idx, zbf, pool_out, out);
    } else {
        k_prep <<<400, 256, 0, stream>>>(x, xpool_part, w, wT2);  // colsum blocks only
        k_pool <<<1, 128, 0, stream>>>(xpool_part, w, pool_out);
        k_fb   <<<NBAT, 128, 0, stream>>>(x, idx, w, pool_out, out);
    }
}